// Round 2
// baseline (4789.838 us; speedup 1.0000x reference)
//
#include <hip/hip_runtime.h>
#include <float.h>
#include <math.h>

// Net_69664369541652: 8-iteration matching pursuit.
// One block per (b,t) position (2048 blocks, 512 threads). All per-position
// state (x_res, y_res, hmask) lives in LDS / registers across the 8
// iterations. Global interaction: loss sum (double atomicAdd, 1/block) and
// nonzero count of y (int atomicAdd, 1/wave, once).
// [Round 1: identical resubmit — round-0 bench hit GPUAcquisitionTimeout,
//  no signal to act on.]

#define NITER 8

__device__ __forceinline__ void argmaxStep(float &v, int &i, float v2, int i2) {
    // max with first-index (lower-index) tie break, matching jnp.argmax / top_k
    if (v2 > v || (v2 == v && i2 < i)) { v = v2; i = i2; }
}

__global__ __launch_bounds__(512, 2)
void mp_kernel(const float* __restrict__ x, const float* __restrict__ y,
               const float* __restrict__ encw, const float* __restrict__ encb,
               const float* __restrict__ decw, const float* __restrict__ decb,
               double* __restrict__ lossSum, int* __restrict__ nzCount)
{
    const int tid  = threadIdx.x;
    const int bt   = blockIdx.x;
    const int lane = tid & 63;
    const int wid  = tid >> 6;
    const int c    = tid;            // encoder channel owned by this thread

    __shared__ __align__(16) float yap[256];   // zero-padded y_align_attn: yap[80+j]=ya[j]
    __shared__ float xr[80], yr[80], yy[80];   // x_res, y_res, original y
    __shared__ __align__(16) float hrow[512];  // selected h row (after prev-mask zeroing)
    __shared__ float xext[160];
    __shared__ float eparts[81 * 8];
    __shared__ float selVal[64];
    __shared__ int   selIdx[64];
    __shared__ float rv[8];
    __shared__ int   ri[8];
    __shared__ int   cnt;
    __shared__ int   theta_s, hind_s;
    __shared__ float ysq_s, bf1, bf2;

    float myy = 0.f;
    if (tid < 80) {
        xr[tid] = x[bt * 80 + tid];
        myy = y[bt * 80 + tid];
        yr[tid] = myy;
        yy[tid] = myy;
    }
    if (tid < 256) yap[tid] = 0.f;

    // global nonzero count of y (denominator of seq_loss), once
    {
        unsigned long long b = __ballot(tid < 80 && myy != 0.0f);
        if (lane == 0 && wid < 2) {
            int n = (int)__popcll(b);
            if (n) atomicAdd(nzCount, n);
        }
    }

    const float bc = encb[c];
    bool   mprev = false;       // hmask (mask_prev) bit for channel c
    double blockLoss = 0.0;     // accumulated by thread 0 only

    for (int iter = 0; iter < NITER; ++iter) {
        __syncthreads();

        // ---------- ||y_res||^2 ----------
        {
            float v = 0.f;
            if (tid < 80) { float t = yr[tid]; v = t * t; }
            #pragma unroll
            for (int off = 32; off; off >>= 1) v += __shfl_xor(v, off);
            if (lane == 0) rv[wid] = v;
            __syncthreads();
            if (tid == 0) {
                float s = 0.f;
                for (int k = 0; k < 8; ++k) s += rv[k];
                ysq_s = s;
            }
            __syncthreads();
        }

        // ---------- selector: cosine sim over 159 shifts, argmax ----------
        {
            float sv = -FLT_MAX; int si = 0x7fffffff;
            if (tid < 159) {
                int s = tid;
                int jlo = (s - 79 > 0) ? s - 79 : 0;
                int jhi = (s + 1 < 80) ? s + 1 : 80;
                float num = 0.f, wn = 0.f;
                for (int j = jlo; j < jhi; ++j) {
                    float xv = xr[j];
                    num += xv * yr[j + 79 - s];
                    wn  += xv * xv;
                }
                float den = sqrtf(ysq_s) * sqrtf(wn);
                sv = (den == 0.f) ? 0.f : num / den;   // where(denom==0, 0, num/denom)
                si = s;
            }
            #pragma unroll
            for (int off = 32; off; off >>= 1) {
                float v2 = __shfl_xor(sv, off);
                int   i2 = __shfl_xor(si, off);
                argmaxStep(sv, si, v2, i2);
            }
            if (lane == 0) { rv[wid] = sv; ri[wid] = si; }
            __syncthreads();
            if (tid == 0) {
                float bv = rv[0]; int bi = ri[0];
                for (int k = 1; k < 8; ++k) argmaxStep(bv, bi, rv[k], ri[k]);
                theta_s = bi;
            }
            __syncthreads();
        }
        const int theta = theta_s;

        // ---------- softmax attention -> y_align_attn into yap[80..160) ----------
        float yao = 0.f, z = -FLT_MAX;
        if (tid < 80) {
            int j = theta + tid - 79;                  // x_aug[theta, d]
            if (j >= 0 && j < 80) yao = xr[j];
            z = yao * yy[tid];                         // TEMPER = 1
        }
        {
            float zm = z;
            #pragma unroll
            for (int off = 32; off; off >>= 1) zm = fmaxf(zm, __shfl_xor(zm, off));
            if (lane == 0) rv[wid] = zm;
            __syncthreads();
            if (tid == 0) {
                float m = rv[0];
                for (int k = 1; k < 8; ++k) m = fmaxf(m, rv[k]);
                bf1 = m;
            }
            __syncthreads();
        }
        float ez = 0.f;
        if (tid < 80) ez = expf(z - bf1);
        {
            float es = ez;
            #pragma unroll
            for (int off = 32; off; off >>= 1) es += __shfl_xor(es, off);
            if (lane == 0) rv[wid] = es;
            __syncthreads();
            if (tid == 0) {
                float s = 0.f;
                for (int k = 0; k < 8; ++k) s += rv[k];
                bf2 = s;
            }
            __syncthreads();
        }
        if (tid < 80) yap[80 + tid] = yao * (ez / bf2);
        __syncthreads();

        // ---------- encoder conv: h[s,c] = sum_w encw[w,c]*yap[w+s] + b[c] ----------
        // thread owns channel c, accumulators over all 81 shifts (padded to 88).
        // w4 and s0 are both 4-aligned -> yap float4 reads are aligned ds_read_b128
        // broadcasts. Chunks with only zero-pad contributions are skipped
        // (adds exact 0.0 terms only, so pruning is exact).
        float acc[88];
        #pragma unroll
        for (int s = 0; s < 88; ++s) acc[s] = 0.f;
        {
            const float4* yapv = (const float4*)yap;
            const float* wp = encw + c;
            for (int w4 = 0; w4 < 160; w4 += 4) {
                float wv0 = wp[(w4 + 0) * 512];
                float wv1 = wp[(w4 + 1) * 512];
                float wv2 = wp[(w4 + 2) * 512];
                float wv3 = wp[(w4 + 3) * 512];
                #pragma unroll
                for (int chn = 0; chn < 11; ++chn) {
                    const int s0 = chn * 8;
                    if (w4 >= 70 - s0 && w4 < 160 - s0) {
                        int qb = (w4 + s0) >> 2;
                        float4 A = yapv[qb + 0];
                        float4 B = yapv[qb + 1];
                        float4 C = yapv[qb + 2];
                        float yv[12] = {A.x, A.y, A.z, A.w, B.x, B.y, B.z, B.w,
                                        C.x, C.y, C.z, C.w};
                        #pragma unroll
                        for (int ss = 0; ss < 8; ++ss) {
                            acc[s0 + ss] += wv0 * yv[ss + 0];
                            acc[s0 + ss] += wv1 * yv[ss + 1];
                            acc[s0 + ss] += wv2 * yv[ss + 2];
                            acc[s0 + ss] += wv3 * yv[ss + 3];
                        }
                    }
                }
            }
        }

        // ---------- energy pooling: argmax_s sum_c (h)^2 ----------
        #pragma unroll
        for (int s = 0; s < 81; ++s) {
            float h = acc[s] + bc;
            float e = h * h;
            #pragma unroll
            for (int off = 32; off; off >>= 1) e += __shfl_xor(e, off);
            if (lane == 0) eparts[s * 8 + wid] = e;
        }
        __syncthreads();
        {
            float ev = -FLT_MAX; int ei = 0x7fffffff;
            if (tid < 81) {
                float e = 0.f;
                #pragma unroll
                for (int k = 0; k < 8; ++k) e += eparts[tid * 8 + k];
                ev = e; ei = tid;
            }
            #pragma unroll
            for (int off = 32; off; off >>= 1) {
                float v2 = __shfl_xor(ev, off);
                int   i2 = __shfl_xor(ei, off);
                argmaxStep(ev, ei, v2, i2);
            }
            if (lane == 0) { rv[wid] = ev; ri[wid] = ei; }
            __syncthreads();
            if (tid == 0) {
                float bv = rv[0]; int bi = ri[0];
                for (int k = 1; k < 8; ++k) argmaxStep(bv, bi, rv[k], ri[k]);
                hind_s = bi;
            }
            __syncthreads();
        }
        const int hind = hind_s;

        // ---------- select row, apply prev mask, exact top-64 by rank count ----------
        float hv = 0.f;
        #pragma unroll
        for (int s = 0; s < 81; ++s) if (s == hind) hv = acc[s];  // static idx -> cndmask
        hv += bc;
        if (iter > 0 && mprev) hv = 0.f;   // h = where(mask_prev>0, 0, h)
        hrow[c] = hv;
        if (tid == 0) cnt = 0;
        __syncthreads();
        {
            const float k0 = hv * hv;
            int rank = 0;
            const float4* h4 = (const float4*)hrow;
            for (int q = 0; q < 128; ++q) {
                float4 hq = h4[q];
                int cb = q * 4;
                float ka = hq.x * hq.x, kb = hq.y * hq.y;
                float kc = hq.z * hq.z, kd = hq.w * hq.w;
                rank += (ka > k0) || (ka == k0 && (cb + 0) < c);
                rank += (kb > k0) || (kb == k0 && (cb + 1) < c);
                rank += (kc > k0) || (kc == k0 && (cb + 2) < c);
                rank += (kd > k0) || (kd == k0 && (cb + 3) < c);
            }
            bool sel = rank < 64;          // exact lax.top_k tie semantics
            mprev = mprev || sel;          // mask_prev accumulation (>0 test only)
            if (sel) {
                int p = atomicAdd(&cnt, 1);
                selIdx[p] = c;
                selVal[p] = hv;            // h = where(mask_cur>0, h, 0): only kept ones
            }
        }
        __syncthreads();

        // ---------- sparse decoder: x_ext = h_sel @ dec_w + dec_b ----------
        if (tid < 160) {
            float a2 = decb[tid];
            for (int k = 0; k < 64; ++k)
                a2 += selVal[k] * decw[selIdx[k] * 160 + tid];
            xext[tid] = a2;
        }
        __syncthreads();

        // ---------- y_ele gather, loss, residual updates ----------
        float ye = 0.f, yrv = 0.f, lp = 0.f;
        if (tid < 80) {
            ye  = xext[80 - hind + tid];       // offs = 80 - h_ind + i
            yrv = yr[tid];
            float d = ye - yrv;
            lp = (yy[tid] == 0.0f) ? 0.f : d * d;   // seq_mask = (y == 0)
        }
        {
            float ls = lp;
            #pragma unroll
            for (int off = 32; off; off >>= 1) ls += __shfl_xor(ls, off);
            if (lane == 0) rv[wid] = ls;
            __syncthreads();
            if (tid == 0) {
                float s = 0.f;
                for (int k = 0; k < 8; ++k) s += rv[k];
                blockLoss += (double)s;
            }
        }
        float xe = 0.f;
        if (tid < 80) xe = yap[tid + 159 - theta];  // x_ele via zero-padded yap
        __syncthreads();
        if (tid < 80) {
            yr[tid] = yrv - ye;     // y_res -= y_ele
            xr[tid] -= xe;          // x_res -= x_ele
        }
    }

    if (tid == 0) atomicAdd(lossSum, blockLoss);
}

__global__ void finish_kernel(const double* __restrict__ lossSum,
                              const int* __restrict__ nz,
                              float* __restrict__ out)
{
    int n = *nz;
    if (n < 1) n = 1;
    out[0] = (float)(*lossSum / (8.0 * (double)n));
}

extern "C" void kernel_launch(void* const* d_in, const int* in_sizes, int n_in,
                              void* d_out, int out_size, void* d_ws, size_t ws_size,
                              hipStream_t stream) {
    (void)in_sizes; (void)n_in; (void)out_size; (void)ws_size;
    const float* x    = (const float*)d_in[0];
    const float* y    = (const float*)d_in[1];
    const float* encw = (const float*)d_in[2];
    const float* encb = (const float*)d_in[3];
    const float* decw = (const float*)d_in[4];
    const float* decb = (const float*)d_in[5];

    double* lossSum = (double*)d_ws;
    int*    nz      = (int*)((char*)d_ws + 8);

    hipMemsetAsync(d_ws, 0, 16, stream);
    mp_kernel<<<2048, 512, 0, stream>>>(x, y, encw, encb, decw, decb, lossSum, nz);
    finish_kernel<<<1, 1, 0, stream>>>(lossSum, nz, (float*)d_out);
}

// Round 5
// 3027.692 us; speedup vs baseline: 1.5820x; 1.5820x over previous
//
#include <hip/hip_runtime.h>
#include <float.h>
#include <math.h>

// Net_69664369541652: 8-iteration matching pursuit.
// One block per (b,t) position (2048 blocks, 512 threads). All per-position
// state (x_res, y_res, hmask) lives in LDS / registers across the 8
// iterations.
// Round 3: conv restructured into 3 shift-chunk passes (acc[28] live instead
// of acc[88]) to eliminate the AGPR/scratch spill that round 2's counters
// showed (VGPR=88 with ~120 live values; occupancy 24.5% = 1 block/CU).
// Weight-streamed inner loop: 4 coalesced global weight loads + 8 broadcast
// ds_read_b128 of the zero-padded ya window + 112 static-index FMAs.
// [Rounds 4-5: identical resubmits — infra failures (acquisition timeout,
//  container failed twice); the 3-pass experiment is still unmeasured.]

#define NITER 8

__device__ __forceinline__ void argmaxStep(float &v, int &i, float v2, int i2) {
    // max with first-index (lower-index) tie break, matching jnp.argmax / top_k
    if (v2 > v || (v2 == v && i2 < i)) { v = v2; i = i2; }
}

// One conv pass over shifts [S0, S0+28). h[s,c] = sum_v encw[v,c]*yap[v+s].
// yap is zero outside [80,160), so v4 outside [V4LO,V4HI] contributes exact
// zeros and is skipped. Window W[i] = yap[v4+S0+i], i in [0,32); FMA uses
// W[k+s] (k<4, s<28 -> max index 30). yap max index = V4HI+S0+31 = 187 < 256.
template<int S0, int V4LO, int V4HI>
__device__ __forceinline__ void convPass(const float* __restrict__ wp,
                                         const float4* __restrict__ yap4,
                                         float bc, int lane, int wid,
                                         float* __restrict__ eparts)
{
    float acc[28];
    #pragma unroll
    for (int s = 0; s < 28; ++s) acc[s] = 0.f;

    #pragma unroll 2
    for (int v4 = V4LO; v4 <= V4HI; v4 += 4) {
        float wv0 = wp[(v4 + 0) * 512];
        float wv1 = wp[(v4 + 1) * 512];
        float wv2 = wp[(v4 + 2) * 512];
        float wv3 = wp[(v4 + 3) * 512];
        const float4* base = yap4 + ((v4 + S0) >> 2);
        float W[32];
        #pragma unroll
        for (int q = 0; q < 8; ++q) {
            float4 t = base[q];
            W[4 * q + 0] = t.x; W[4 * q + 1] = t.y;
            W[4 * q + 2] = t.z; W[4 * q + 3] = t.w;
        }
        #pragma unroll
        for (int s = 0; s < 28; ++s) {
            acc[s] += wv0 * W[s + 0];
            acc[s] += wv1 * W[s + 1];
            acc[s] += wv2 * W[s + 2];
            acc[s] += wv3 * W[s + 3];
        }
    }

    // energy partials: e[s] = sum_c (h[s,c])^2, wave-level partial per wid
    #pragma unroll
    for (int s = 0; s < 28; ++s) {
        if (S0 + s < 81) {
            float h = acc[s] + bc;
            float e = h * h;
            #pragma unroll
            for (int off = 32; off; off >>= 1) e += __shfl_xor(e, off);
            if (lane == 0) eparts[(S0 + s) * 8 + wid] = e;
        }
    }
}

__global__ __launch_bounds__(512, 4)
void mp_kernel(const float* __restrict__ x, const float* __restrict__ y,
               const float* __restrict__ encw, const float* __restrict__ encb,
               const float* __restrict__ decw, const float* __restrict__ decb,
               double* __restrict__ lossSum, int* __restrict__ nzCount)
{
    const int tid  = threadIdx.x;
    const int bt   = blockIdx.x;
    const int lane = tid & 63;
    const int wid  = tid >> 6;
    const int c    = tid;            // encoder channel owned by this thread

    __shared__ __align__(16) float yap[256];   // zero-padded y_align_attn: yap[80+j]=ya[j]
    __shared__ float xr[80], yr[80], yy[80];   // x_res, y_res, original y
    __shared__ __align__(16) float hrow[512];  // selected h row (after prev-mask zeroing)
    __shared__ float xext[160];
    __shared__ float eparts[81 * 8];
    __shared__ float selVal[64];
    __shared__ int   selIdx[64];
    __shared__ float rv[8];
    __shared__ int   ri[8];
    __shared__ int   cnt;
    __shared__ int   theta_s, hind_s;
    __shared__ float ysq_s, bf1, bf2;

    float myy = 0.f;
    if (tid < 80) {
        xr[tid] = x[bt * 80 + tid];
        myy = y[bt * 80 + tid];
        yr[tid] = myy;
        yy[tid] = myy;
    }
    if (tid < 256) yap[tid] = 0.f;

    // global nonzero count of y (denominator of seq_loss), once
    {
        unsigned long long b = __ballot(tid < 80 && myy != 0.0f);
        if (lane == 0 && wid < 2) {
            int n = (int)__popcll(b);
            if (n) atomicAdd(nzCount, n);
        }
    }

    const float bc = encb[c];
    bool   mprev = false;       // hmask (mask_prev) bit for channel c
    double blockLoss = 0.0;     // accumulated by thread 0 only

    for (int iter = 0; iter < NITER; ++iter) {
        __syncthreads();

        // ---------- ||y_res||^2 ----------
        {
            float v = 0.f;
            if (tid < 80) { float t = yr[tid]; v = t * t; }
            #pragma unroll
            for (int off = 32; off; off >>= 1) v += __shfl_xor(v, off);
            if (lane == 0) rv[wid] = v;
            __syncthreads();
            if (tid == 0) {
                float s = 0.f;
                for (int k = 0; k < 8; ++k) s += rv[k];
                ysq_s = s;
            }
            __syncthreads();
        }

        // ---------- selector: cosine sim over 159 shifts, argmax ----------
        {
            float sv = -FLT_MAX; int si = 0x7fffffff;
            if (tid < 159) {
                int s = tid;
                int jlo = (s - 79 > 0) ? s - 79 : 0;
                int jhi = (s + 1 < 80) ? s + 1 : 80;
                float num = 0.f, wn = 0.f;
                for (int j = jlo; j < jhi; ++j) {
                    float xv = xr[j];
                    num += xv * yr[j + 79 - s];
                    wn  += xv * xv;
                }
                float den = sqrtf(ysq_s) * sqrtf(wn);
                sv = (den == 0.f) ? 0.f : num / den;   // where(denom==0, 0, num/denom)
                si = s;
            }
            #pragma unroll
            for (int off = 32; off; off >>= 1) {
                float v2 = __shfl_xor(sv, off);
                int   i2 = __shfl_xor(si, off);
                argmaxStep(sv, si, v2, i2);
            }
            if (lane == 0) { rv[wid] = sv; ri[wid] = si; }
            __syncthreads();
            if (tid == 0) {
                float bv = rv[0]; int bi = ri[0];
                for (int k = 1; k < 8; ++k) argmaxStep(bv, bi, rv[k], ri[k]);
                theta_s = bi;
            }
            __syncthreads();
        }
        const int theta = theta_s;

        // ---------- softmax attention -> y_align_attn into yap[80..160) ----------
        float yao = 0.f, z = -FLT_MAX;
        if (tid < 80) {
            int j = theta + tid - 79;                  // x_aug[theta, d]
            if (j >= 0 && j < 80) yao = xr[j];
            z = yao * yy[tid];                         // TEMPER = 1
        }
        {
            float zm = z;
            #pragma unroll
            for (int off = 32; off; off >>= 1) zm = fmaxf(zm, __shfl_xor(zm, off));
            if (lane == 0) rv[wid] = zm;
            __syncthreads();
            if (tid == 0) {
                float m = rv[0];
                for (int k = 1; k < 8; ++k) m = fmaxf(m, rv[k]);
                bf1 = m;
            }
            __syncthreads();
        }
        float ez = 0.f;
        if (tid < 80) ez = expf(z - bf1);
        {
            float es = ez;
            #pragma unroll
            for (int off = 32; off; off >>= 1) es += __shfl_xor(es, off);
            if (lane == 0) rv[wid] = es;
            __syncthreads();
            if (tid == 0) {
                float s = 0.f;
                for (int k = 0; k < 8; ++k) s += rv[k];
                bf2 = s;
            }
            __syncthreads();
        }
        if (tid < 80) yap[80 + tid] = yao * (ez / bf2);
        __syncthreads();

        // ---------- encoder conv, 3 shift-chunk passes (28 acc live each) ----
        {
            const float* wp = encw + c;
            const float4* yap4 = (const float4*)yap;
            convPass< 0, 52, 156>(wp, yap4, bc, lane, wid, eparts);
            convPass<28, 24, 128>(wp, yap4, bc, lane, wid, eparts);
            convPass<56,  0, 100>(wp, yap4, bc, lane, wid, eparts);
        }
        __syncthreads();

        // ---------- energy pooling argmax over 81 shifts ----------
        {
            float ev = -FLT_MAX; int ei = 0x7fffffff;
            if (tid < 81) {
                float e = 0.f;
                #pragma unroll
                for (int k = 0; k < 8; ++k) e += eparts[tid * 8 + k];
                ev = e; ei = tid;
            }
            #pragma unroll
            for (int off = 32; off; off >>= 1) {
                float v2 = __shfl_xor(ev, off);
                int   i2 = __shfl_xor(ei, off);
                argmaxStep(ev, ei, v2, i2);
            }
            if (lane == 0) { rv[wid] = ev; ri[wid] = ei; }
            __syncthreads();
            if (tid == 0) {
                float bv = rv[0]; int bi = ri[0];
                for (int k = 1; k < 8; ++k) argmaxStep(bv, bi, rv[k], ri[k]);
                hind_s = bi;
            }
            __syncthreads();
        }
        const int hind = hind_s;

        // ---------- recompute h[hind, c] (80 FMAs; replaces keeping 88 acc) --
        float hv = bc;
        {
            const float* wp = encw + c;
            #pragma unroll 4
            for (int v = 80 - hind; v < 160 - hind; ++v)
                hv += wp[v * 512] * yap[v + hind];
        }
        if (iter > 0 && mprev) hv = 0.f;   // h = where(mask_prev>0, 0, h)
        hrow[c] = hv;
        if (tid == 0) cnt = 0;
        __syncthreads();

        // ---------- exact top-64 by rank count ----------
        {
            const float k0 = hv * hv;
            int rank = 0;
            const float4* h4 = (const float4*)hrow;
            for (int q = 0; q < 128; ++q) {
                float4 hq = h4[q];
                int cb = q * 4;
                float ka = hq.x * hq.x, kb = hq.y * hq.y;
                float kc = hq.z * hq.z, kd = hq.w * hq.w;
                rank += (ka > k0) || (ka == k0 && (cb + 0) < c);
                rank += (kb > k0) || (kb == k0 && (cb + 1) < c);
                rank += (kc > k0) || (kc == k0 && (cb + 2) < c);
                rank += (kd > k0) || (kd == k0 && (cb + 3) < c);
            }
            bool sel = rank < 64;          // exact lax.top_k tie semantics
            mprev = mprev || sel;          // mask_prev accumulation (>0 test only)
            if (sel) {
                int p = atomicAdd(&cnt, 1);
                selIdx[p] = c;
                selVal[p] = hv;            // h = where(mask_cur>0, h, 0): only kept ones
            }
        }
        __syncthreads();

        // ---------- sparse decoder: x_ext = h_sel @ dec_w + dec_b ----------
        if (tid < 160) {
            float a2 = decb[tid];
            for (int k = 0; k < 64; ++k)
                a2 += selVal[k] * decw[selIdx[k] * 160 + tid];
            xext[tid] = a2;
        }
        __syncthreads();

        // ---------- y_ele gather, loss, residual updates ----------
        float ye = 0.f, yrv = 0.f, lp = 0.f;
        if (tid < 80) {
            ye  = xext[80 - hind + tid];       // offs = 80 - h_ind + i
            yrv = yr[tid];
            float d = ye - yrv;
            lp = (yy[tid] == 0.0f) ? 0.f : d * d;   // seq_mask = (y == 0)
        }
        {
            float ls = lp;
            #pragma unroll
            for (int off = 32; off; off >>= 1) ls += __shfl_xor(ls, off);
            if (lane == 0) rv[wid] = ls;
            __syncthreads();
            if (tid == 0) {
                float s = 0.f;
                for (int k = 0; k < 8; ++k) s += rv[k];
                blockLoss += (double)s;
            }
        }
        float xe = 0.f;
        if (tid < 80) xe = yap[tid + 159 - theta];  // x_ele via zero-padded yap
        __syncthreads();
        if (tid < 80) {
            yr[tid] = yrv - ye;     // y_res -= y_ele
            xr[tid] -= xe;          // x_res -= x_ele
        }
    }

    if (tid == 0) atomicAdd(lossSum, blockLoss);
}

__global__ void finish_kernel(const double* __restrict__ lossSum,
                              const int* __restrict__ nz,
                              float* __restrict__ out)
{
    int n = *nz;
    if (n < 1) n = 1;
    out[0] = (float)(*lossSum / (8.0 * (double)n));
}

extern "C" void kernel_launch(void* const* d_in, const int* in_sizes, int n_in,
                              void* d_out, int out_size, void* d_ws, size_t ws_size,
                              hipStream_t stream) {
    (void)in_sizes; (void)n_in; (void)out_size; (void)ws_size;
    const float* x    = (const float*)d_in[0];
    const float* y    = (const float*)d_in[1];
    const float* encw = (const float*)d_in[2];
    const float* encb = (const float*)d_in[3];
    const float* decw = (const float*)d_in[4];
    const float* decb = (const float*)d_in[5];

    double* lossSum = (double*)d_ws;
    int*    nz      = (int*)((char*)d_ws + 8);

    hipMemsetAsync(d_ws, 0, 16, stream);
    mp_kernel<<<2048, 512, 0, stream>>>(x, y, encw, encb, decw, decb, lossSum, nz);
    finish_kernel<<<1, 1, 0, stream>>>(lossSum, nz, (float*)d_out);
}